// Round 12
// baseline (199.756 us; speedup 1.0000x reference)
//
#include <hip/hip_runtime.h>
#include <hip/hip_cooperative_groups.h>
#include <hip/hip_bf16.h>
#include <math.h>

namespace cg = cooperative_groups;

#define DD 64
#define BROWS 64            // rows per bucket
#define BSH 6               // log2(BROWS)
#define MAXB 1024           // max buckets supported
#define CAPB 1536           // fixed bucket capacity (mean + >8 sigma headroom)
#define BINC 3072           // edges per bin work-item (6 per thread at 512 thr)
#define LROWS 128           // rows per linear work-item (8 waves x 16)
typedef unsigned long long u64;
typedef unsigned int u32;
typedef unsigned short u16;
typedef __fp16 f16x2 __attribute__((ext_vector_type(2)));

// ---------------------------------------------------------------------------
// Single cooperative kernel: phase0 zero -> sync -> phase1 {bin|linear} work
// queue -> fence+sync -> phase2 bucket-aggregate + fused epilogue.
// All techniques carried from R11 (one-pass LDS-rank bin; f16-dot linear with
// broadcast LDS x; sort-then-register-accumulate bagg; spill list for safety).
// ---------------------------------------------------------------------------
__global__ __launch_bounds__(512) void hgcn_coop(const float* __restrict__ x,
                                                 const float* __restrict__ W,
                                                 __hip_bfloat16* __restrict__ he,
                                                 const int* __restrict__ ei,
                                                 const float* __restrict__ ew,
                                                 int* __restrict__ bcur,
                                                 u64* __restrict__ stage,
                                                 u64* __restrict__ spill,
                                                 int* __restrict__ nspill,
                                                 float* __restrict__ out,
                                                 int n, int ne, int nbin, int nlinc, int nb) {
  cg::grid_group grid = cg::this_grid();
  const int tid = threadIdx.x;
  const int G = gridDim.x;
  __shared__ int h[MAXB], gp[MAXB];
  __shared__ u64 edr[CAPB], ed[CAPB];
  __shared__ f16x2 xsh[8][32];
  __shared__ int lh[BROWS + 1], lcur[BROWS];

  // ---------------- phase 0: zero cursors + spill counter -------------------
  for (int i = blockIdx.x * 512 + tid; i < MAXB + 1; i += G * 512) {
    if (i < MAXB) bcur[i] = 0;
    else nspill[0] = 0;
  }
  grid.sync();

  // ---------------- phase 1: unified {bin | linear} work queue --------------
  for (int wi = blockIdx.x; wi < nbin + nlinc; wi += G) {
    if (wi < nbin) {
      // ------------------------------ bin ----------------------------------
      __syncthreads();                 // guard h/gp reuse across iterations
      h[tid] = 0; h[tid + 512] = 0;
      __syncthreads();
      const int eb = wi * BINC;
      const int m = min(BINC, ne - eb);
      int r[6], c[6], rk[6];
      float w[6];
      int cnt2 = 0;
      #pragma unroll
      for (int k = 0; k < 6; ++k) {
        const int i = tid + k * 512;
        if (i < m) {
          r[k] = ei[eb + i];
          c[k] = ei[ne + eb + i];
          w[k] = ew[eb + i];
          rk[k] = atomicAdd(&h[r[k] >> BSH], 1);   // rank within work-item
          cnt2 = k + 1;
        }
      }
      __syncthreads();
      {
        const int v0 = h[tid];
        gp[tid] = v0 ? atomicAdd(&bcur[tid], v0) : 0;
        const int v1 = h[tid + 512];
        gp[tid + 512] = v1 ? atomicAdd(&bcur[tid + 512], v1) : 0;
      }
      __syncthreads();
      for (int k = 0; k < cnt2; ++k) {
        const int b = r[k] >> BSH;
        const int pos = gp[b] + rk[k];
        if (pos < CAPB) {
          stage[(size_t)b * CAPB + pos] =
              ((u64)__float_as_uint(w[k]) << 32) | ((u32)(r[k] & (BROWS - 1)) << 16) | (u32)c[k];
        } else {
          const int sp = atomicAdd(nspill, 1);
          spill[sp] = ((u64)__float_as_uint(w[k]) << 32) | ((u32)(r[k] & 0xffff) << 16) | (u32)c[k];
        }
      }
    } else {
      // ----------------------------- linear --------------------------------
      const int lb = wi - nbin;
      const int wave = tid >> 6, lane = tid & 63;
      f16x2 Wh[32];                     // W column `lane` as packed f16 pairs
      #pragma unroll
      for (int m4 = 0; m4 < 16; ++m4) {
        const float4 wv = *reinterpret_cast<const float4*>(W + lane * 64 + m4 * 4);
        Wh[2 * m4]     = __builtin_amdgcn_cvt_pkrtz(wv.x, wv.y);
        Wh[2 * m4 + 1] = __builtin_amdgcn_cvt_pkrtz(wv.z, wv.w);
      }
      const int rbase = lb * LROWS + wave * 16;
      for (int q = 0; q < 16; ++q) {
        const int row = rbase + q;
        if (row >= n) break;                        // uniform per wave
        const float xv = x[(size_t)row * DD + lane];
        float nx2 = xv * xv;
        #pragma unroll
        for (int mm = 1; mm < 64; mm <<= 1) nx2 += __shfl_xor(nx2, mm);
        const float nx = fmaxf(sqrtf(nx2), 1e-15f);
        const float z  = fminf(nx, 1.f - 1e-7f);
        const float s  = 0.5f * __logf((1.f + z) / (1.f - z)) / nx;
        const float xo = __shfl_xor(xv, 1);
        if (!(lane & 1)) xsh[wave][lane >> 1] = __builtin_amdgcn_cvt_pkrtz(xv, xo);
        float acc = 0.f;
        #pragma unroll
        for (int m2 = 0; m2 < 32; ++m2)
          acc = __builtin_amdgcn_fdot2(xsh[wave][m2], Wh[m2], acc, false);
        he[(size_t)row * DD + lane] = __float2bfloat16(acc * s);
      }
    }
  }
  __threadfence();
  grid.sync();

  // ---------------- phase 2: bucket aggregate + fused epilogue --------------
  const int ns = nspill[0];
  for (int b = blockIdx.x; b < nb; b += G) {
    __syncthreads();                   // guard edr/ed reuse across buckets
    const u64* sb = stage + (size_t)b * CAPB;
    const int cnt = min(bcur[b], CAPB);
    for (int i = tid; i < cnt; i += 512) edr[i] = sb[i];   // single global read
    if (tid < BROWS) lcur[tid] = 0;
    __syncthreads();
    for (int i = tid; i < cnt; i += 512)
      atomicAdd(&lcur[(int)((edr[i] >> 16) & (BROWS - 1))], 1);
    __syncthreads();
    if (tid < 64) {
      const int v = lcur[tid];
      int sc = v;
      #pragma unroll
      for (int d = 1; d < 64; d <<= 1) {
        const int u2 = __shfl_up(sc, d);
        if (tid >= d) sc += u2;
      }
      lh[tid] = sc - v;
      lcur[tid] = sc - v;
      if (tid == 63) lh[64] = sc;
    }
    __syncthreads();
    for (int i = tid; i < cnt; i += 512) {
      const u64 p = edr[i];
      const int rl = (int)((p >> 16) & (BROWS - 1));
      const int pos = atomicAdd(&lcur[rl], 1);
      ed[pos] = p;
    }
    __syncthreads();

    const int row = tid >> 3;          // 0..63
    const int l = tid & 7;             // 8 lanes split D=64 as 8x8
    float a[8] = {0.f, 0.f, 0.f, 0.f, 0.f, 0.f, 0.f, 0.f};

    int j = lh[row];
    const int je = lh[row + 1];
    uint4 q = {0, 0, 0, 0};
    float w = 0.f;
    if (j < je) {
      const u64 p = ed[j];
      w = __uint_as_float((u32)(p >> 32));
      q = reinterpret_cast<const uint4*>(he + ((size_t)(p & 0xffffu) << 6))[l];
    }
    while (j < je) {
      const uint4 qc = q;
      const float wc = w;
      const int jn = j + 1;
      if (jn < je) {
        const u64 p = ed[jn];
        w = __uint_as_float((u32)(p >> 32));
        q = reinterpret_cast<const uint4*>(he + ((size_t)(p & 0xffffu) << 6))[l];
      }
      a[0] = fmaf(wc, __uint_as_float(qc.x << 16), a[0]);
      a[1] = fmaf(wc, __uint_as_float(qc.x & 0xffff0000u), a[1]);
      a[2] = fmaf(wc, __uint_as_float(qc.y << 16), a[2]);
      a[3] = fmaf(wc, __uint_as_float(qc.y & 0xffff0000u), a[3]);
      a[4] = fmaf(wc, __uint_as_float(qc.z << 16), a[4]);
      a[5] = fmaf(wc, __uint_as_float(qc.z & 0xffff0000u), a[5]);
      a[6] = fmaf(wc, __uint_as_float(qc.w << 16), a[6]);
      a[7] = fmaf(wc, __uint_as_float(qc.w & 0xffff0000u), a[7]);
      j = jn;
    }

    // spill-scan: normally ns == 0 -> skip.
    for (int sidx = 0; sidx < ns; ++sidx) {
      const u64 p = spill[sidx];
      const int grow = (int)((p >> 16) & 0xffffu);
      if ((grow >> BSH) != b) continue;
      if ((grow & (BROWS - 1)) != row) continue;
      const float ww = __uint_as_float((u32)(p >> 32));
      const uint4 qq = reinterpret_cast<const uint4*>(he + ((size_t)(p & 0xffffu) << 6))[l];
      a[0] = fmaf(ww, __uint_as_float(qq.x << 16), a[0]);
      a[1] = fmaf(ww, __uint_as_float(qq.x & 0xffff0000u), a[1]);
      a[2] = fmaf(ww, __uint_as_float(qq.y << 16), a[2]);
      a[3] = fmaf(ww, __uint_as_float(qq.y & 0xffff0000u), a[3]);
      a[4] = fmaf(ww, __uint_as_float(qq.z << 16), a[4]);
      a[5] = fmaf(ww, __uint_as_float(qq.z & 0xffff0000u), a[5]);
      a[6] = fmaf(ww, __uint_as_float(qq.w << 16), a[6]);
      a[7] = fmaf(ww, __uint_as_float(qq.w & 0xffff0000u), a[7]);
    }

    // epilogue: out = proj(expmap0(relu(acc)))  (8-lane reduce for the norm)
    float ss = 0.f;
    #pragma unroll
    for (int k = 0; k < 8; ++k) { a[k] = fmaxf(a[k], 0.f); ss = fmaf(a[k], a[k], ss); }
    ss += __shfl_xor(ss, 1); ss += __shfl_xor(ss, 2); ss += __shfl_xor(ss, 4);
    const float nu = fmaxf(sqrtf(ss), 1e-15f);
    const float th = tanhf(nu);
    const float maxn = 1.0f - 4e-3f;
    const float scale = (th > maxn) ? (maxn / nu) : (th / nu);
    const int grow = (b << BSH) + row;
    if (grow < n) {
      float4* op = reinterpret_cast<float4*>(out + (size_t)grow * DD + (size_t)l * 8);
      op[0] = float4{a[0] * scale, a[1] * scale, a[2] * scale, a[3] * scale};
      op[1] = float4{a[4] * scale, a[5] * scale, a[6] * scale, a[7] * scale};
    }
  }
}

// ---------------------------------------------------------------------------
// Deep fallback (tiny ws): atomic scatter path, fp32 (R1 structure).
// ---------------------------------------------------------------------------
__global__ __launch_bounds__(256) void hgcn_linf32(const float* __restrict__ x,
                                                   const float* __restrict__ W,
                                                   float* __restrict__ he, int n) {
  __shared__ float Wl[64][68];
  __shared__ float xs[4][64];
  const int tid = threadIdx.x;
  for (int i = tid; i < 64 * 64; i += 256) Wl[i >> 6][i & 63] = W[i];
  const int wave = tid >> 6, lane = tid & 63;
  const int row = blockIdx.x * 4 + wave;
  float xv = 0.f;
  if (row < n) xv = x[row * DD + lane];
  xs[wave][lane] = xv;
  __syncthreads();
  if (row >= n) return;
  float nx2 = xv * xv;
  #pragma unroll
  for (int m = 1; m < 64; m <<= 1) nx2 += __shfl_xor(nx2, m);
  const float nx = fmaxf(sqrtf(nx2), 1e-15f);
  const float s = atanhf(fminf(nx, 1.f - 1e-7f)) / nx;
  const int j0 = (lane >> 3) & 7;
  float acc = 0.f;
  #pragma unroll
  for (int jj = 0; jj < 16; ++jj) {
    const int k = ((jj + j0) & 15) << 2;
    const float4 xk = *reinterpret_cast<const float4*>(&xs[wave][k]);
    const float4 wk = *reinterpret_cast<const float4*>(&Wl[lane][k]);
    acc = fmaf(xk.x, wk.x, acc); acc = fmaf(xk.y, wk.y, acc);
    acc = fmaf(xk.z, wk.z, acc); acc = fmaf(xk.w, wk.w, acc);
  }
  he[row * DD + lane] = acc * s;
}

__global__ __launch_bounds__(256) void hgcn_zero(float* __restrict__ p, int n4) {
  const int i = blockIdx.x * 256 + threadIdx.x;
  if (i < n4) reinterpret_cast<float4*>(p)[i] = float4{0.f, 0.f, 0.f, 0.f};
}

__global__ __launch_bounds__(256) void hgcn_scatter(const float* __restrict__ he,
                                                    const int* __restrict__ ei,
                                                    const float* __restrict__ ew,
                                                    float* __restrict__ sup, int ne) {
  const int t = blockIdx.x * 256 + threadIdx.x;
  const int e = t >> 4, l = t & 15;
  if (e >= ne) return;
  const int row = ei[e];
  const int col = ei[ne + e];
  const float w = ew[e];
  const float4 v = *reinterpret_cast<const float4*>(he + (size_t)col * DD + l * 4);
  float* dst = sup + (size_t)row * DD + l * 4;
  unsafeAtomicAdd(dst + 0, w * v.x);
  unsafeAtomicAdd(dst + 1, w * v.y);
  unsafeAtomicAdd(dst + 2, w * v.z);
  unsafeAtomicAdd(dst + 3, w * v.w);
}

__global__ __launch_bounds__(256) void hgcn_final(const float* __restrict__ sup,
                                                  float* __restrict__ out, int n) {
  const int t = blockIdx.x * 256 + threadIdx.x;
  const int r = t >> 4, l = t & 15;
  if (r >= n) return;
  float4 v = *reinterpret_cast<const float4*>(sup + (size_t)r * DD + l * 4);
  v.x = fmaxf(v.x, 0.f); v.y = fmaxf(v.y, 0.f);
  v.z = fmaxf(v.z, 0.f); v.w = fmaxf(v.w, 0.f);
  float p = v.x*v.x + v.y*v.y + v.z*v.z + v.w*v.w;
  p += __shfl_xor(p, 1); p += __shfl_xor(p, 2);
  p += __shfl_xor(p, 4); p += __shfl_xor(p, 8);
  const float nu = fmaxf(sqrtf(p), 1e-15f);
  const float th = tanhf(nu);
  float scale = th / nu;
  const float maxn = 1.0f - 4e-3f;
  if (th > maxn) scale = maxn / nu;
  float4 o = {v.x*scale, v.y*scale, v.z*scale, v.w*scale};
  *reinterpret_cast<float4*>(out + (size_t)r * DD + l * 4) = o;
}

extern "C" void kernel_launch(void* const* d_in, const int* in_sizes, int n_in,
                              void* d_out, int out_size, void* d_ws, size_t ws_size,
                              hipStream_t stream) {
  const float* x  = (const float*)d_in[0];
  const float* W  = (const float*)d_in[1];
  const float* ew = (const float*)d_in[2];
  const int*   ei = (const int*)d_in[3];
  const int n  = in_sizes[0] / DD;          // 50000
  const int ne = in_sizes[2];               // 800000
  const int nb = (n + BROWS - 1) / BROWS;   // buckets (782)

  // ws layout (16B-aligned blocks)
  size_t off_he    = 0;
  size_t off_stage = off_he + (((size_t)n * DD * 2 + 15) / 16) * 16;
  size_t off_spill = off_stage + (size_t)MAXB * CAPB * 8;
  size_t off_bcur  = off_spill + (size_t)ne * 8;
  size_t off_nsp   = off_bcur + MAXB * 4;
  size_t need      = off_nsp + 64;

  // performance guard only (overflow is correctness-safe via spill):
  const size_t mean = (size_t)ne / (size_t)nb;
  size_t sig = 1;
  while (sig * sig < mean) ++sig;           // ceil(sqrt(mean))
  const bool capOK = mean + 8 * sig <= CAPB;

  int occ = 0;
  hipError_t qerr = hipOccupancyMaxActiveBlocksPerMultiprocessor(&occ, hgcn_coop, 512, 0);
  const bool coopOK = (qerr == hipSuccess && occ >= 1);

  if (ws_size >= need && n <= 65535 && nb <= MAXB && capOK && coopOK) {
    __hip_bfloat16* he = (__hip_bfloat16*)((char*)d_ws + off_he);
    u64* stage  = (u64*)((char*)d_ws + off_stage);
    u64* spill  = (u64*)((char*)d_ws + off_spill);
    int* bcur   = (int*)((char*)d_ws + off_bcur);
    int* nspill = (int*)((char*)d_ws + off_nsp);
    float* out  = (float*)d_out;

    int nbin  = (ne + BINC - 1) / BINC;             // 261
    int nlinc = (n + LROWS - 1) / LROWS;            // 391
    int G = occ * 256;
    if (G > 512) G = 512;

    void* args[] = {(void*)&x, (void*)&W, (void*)&he, (void*)&ei, (void*)&ew,
                    (void*)&bcur, (void*)&stage, (void*)&spill, (void*)&nspill,
                    (void*)&out, (void*)&n, (void*)&ne, (void*)&nbin, (void*)&nlinc,
                    (void*)&nb};
    hipLaunchCooperativeKernel((void*)hgcn_coop, dim3(G), dim3(512), args, 0, stream);
  } else {
    float* he  = (float*)d_out;
    float* sup = (float*)d_ws;
    float* out = (float*)d_out;
    const int n4 = n * DD / 4;
    hipLaunchKernelGGL(hgcn_zero,    dim3((n4 + 255) / 256),       dim3(256), 0, stream, sup, n4);
    hipLaunchKernelGGL(hgcn_linf32,  dim3((n + 3) / 4),            dim3(256), 0, stream, x, W, he, n);
    hipLaunchKernelGGL(hgcn_scatter, dim3((ne * 16 + 255) / 256),  dim3(256), 0, stream, he, ei, ew, sup, ne);
    hipLaunchKernelGGL(hgcn_final,   dim3((n * 16 + 255) / 256),   dim3(256), 0, stream, sup, out, n);
  }
}

// Round 13
// 60.846 us; speedup vs baseline: 3.2830x; 3.2830x over previous
//
#include <hip/hip_runtime.h>
#include <hip/hip_bf16.h>
#include <math.h>

#define DD 64
#define BROWS 64            // rows per bucket
#define BSH 6               // log2(BROWS)
#define MAXB 1024           // max buckets supported
#define CAPB 1536           // fixed bucket capacity (mean + >8 sigma headroom)
#define BINB 512            // bin block threads
#define BINC 3072           // edges per bin block (6 per thread)
#define LROWS 128           // rows per linear block (8 waves x 16)
typedef unsigned long long u64;
typedef unsigned int u32;
typedef unsigned short u16;
typedef __fp16 f16x2 __attribute__((ext_vector_type(2)));

// ---------------------------------------------------------------------------
// K0: zero bucket cursors + spill counter (1 block; precedes linbin in-stream).
// ---------------------------------------------------------------------------
__global__ __launch_bounds__(1024) void hgcn_zero0(int* __restrict__ bcur,
                                                   int* __restrict__ nspill) {
  const int i = threadIdx.x;
  if (i < MAXB) bcur[i] = 0;
  if (i == 0) nspill[0] = 0;
}

// ---------------------------------------------------------------------------
// Fused linear+bin (disjoint inputs -> blocks co-schedule). R11 structure.
// bin: ONE LDS-atomic pass (hist atomicAdd returns local rank).
// linear: f16-dot GEMM, W column in VGPRs, x broadcast via LDS; 16-row loop
// now predicated (no break) so independent row loads software-pipeline.
// ---------------------------------------------------------------------------
__global__ __launch_bounds__(512) void hgcn_linbin(const float* __restrict__ x,
                                                   const float* __restrict__ W,
                                                   __hip_bfloat16* __restrict__ he,
                                                   const int* __restrict__ ei,
                                                   const float* __restrict__ ew,
                                                   int* __restrict__ bcur,
                                                   u64* __restrict__ stage,
                                                   u64* __restrict__ spill,
                                                   int* __restrict__ nspill,
                                                   int n, int ne, int nbin) {
  const int tid = threadIdx.x;
  if ((int)blockIdx.x < nbin) {
    // ------------------------------ bin ------------------------------------
    __shared__ int h[MAXB], gp[MAXB];
    h[tid] = 0; h[tid + 512] = 0;
    __syncthreads();
    const int eb = blockIdx.x * BINC;
    const int m = min(BINC, ne - eb);
    int r[6], c[6], rk[6];
    float w[6];
    int cnt = 0;
    #pragma unroll
    for (int k = 0; k < 6; ++k) {
      const int i = tid + k * BINB;
      if (i < m) {
        r[k] = ei[eb + i];
        c[k] = ei[ne + eb + i];
        w[k] = ew[eb + i];
        rk[k] = atomicAdd(&h[r[k] >> BSH], 1);   // rank within block
        cnt = k + 1;
      }
    }
    __syncthreads();
    {
      const int v0 = h[tid];
      gp[tid] = v0 ? atomicAdd(&bcur[tid], v0) : 0;
      const int v1 = h[tid + 512];
      gp[tid + 512] = v1 ? atomicAdd(&bcur[tid + 512], v1) : 0;
    }
    __syncthreads();
    for (int k = 0; k < cnt; ++k) {
      const int b = r[k] >> BSH;
      const int pos = gp[b] + rk[k];
      if (pos < CAPB) {
        stage[(size_t)b * CAPB + pos] =
            ((u64)__float_as_uint(w[k]) << 32) | ((u32)(r[k] & (BROWS - 1)) << 16) | (u32)c[k];
      } else {
        const int sp = atomicAdd(nspill, 1);
        spill[sp] = ((u64)__float_as_uint(w[k]) << 32) | ((u32)(r[k] & 0xffff) << 16) | (u32)c[k];
      }
    }
  } else {
    // ----------------------------- linear ----------------------------------
    __shared__ f16x2 xsh[8][32];
    const int lb = (int)blockIdx.x - nbin;
    const int wave = tid >> 6, lane = tid & 63;
    f16x2 Wh[32];                       // W column `lane` as packed f16 pairs
    #pragma unroll
    for (int m4 = 0; m4 < 16; ++m4) {
      const float4 wv = *reinterpret_cast<const float4*>(W + lane * 64 + m4 * 4);
      Wh[2 * m4]     = __builtin_amdgcn_cvt_pkrtz(wv.x, wv.y);
      Wh[2 * m4 + 1] = __builtin_amdgcn_cvt_pkrtz(wv.z, wv.w);
    }
    const int rbase = lb * LROWS + wave * 16;
    for (int q = 0; q < 16; ++q) {
      const int row = rbase + q;
      const bool ok = row < n;
      const float xv = ok ? x[(size_t)row * DD + lane] : 0.f;
      float nx2 = xv * xv;
      #pragma unroll
      for (int mm = 1; mm < 64; mm <<= 1) nx2 += __shfl_xor(nx2, mm);
      const float nx = fmaxf(sqrtf(nx2), 1e-15f);
      const float z  = fminf(nx, 1.f - 1e-7f);
      const float s  = 0.5f * __logf((1.f + z) / (1.f - z)) / nx;
      const float xo = __shfl_xor(xv, 1);
      if (!(lane & 1)) xsh[wave][lane >> 1] = __builtin_amdgcn_cvt_pkrtz(xv, xo);
      float acc = 0.f;
      #pragma unroll
      for (int m2 = 0; m2 < 32; ++m2)
        acc = __builtin_amdgcn_fdot2(xsh[wave][m2], Wh[m2], acc, false);
      if (ok) he[(size_t)row * DD + lane] = __float2bfloat16(acc * s);
    }
  }
}

// ---------------------------------------------------------------------------
// Bucket aggregate + fused epilogue (NO fp atomics). R11 structure with a
// depth-2 prefetch ring per slot (2 outstanding he gathers per chain).
// ---------------------------------------------------------------------------
__global__ __launch_bounds__(1024) void hgcn_bagg(const u16* __restrict__ he,
                                                  const u64* __restrict__ stage,
                                                  const int* __restrict__ bcur,
                                                  const u64* __restrict__ spill,
                                                  const int* __restrict__ nspill,
                                                  float* __restrict__ out, int n) {
  __shared__ u64 edr[CAPB];
  __shared__ u64 ed[CAPB];
  __shared__ int lh[BROWS + 1];
  __shared__ int lcur[BROWS];
  const int t = threadIdx.x;
  const int b = blockIdx.x;
  const u64* sb = stage + (size_t)b * CAPB;
  const int cnt = min(bcur[b], CAPB);

  for (int i = t; i < cnt; i += 1024) edr[i] = sb[i];   // single global read
  if (t < BROWS) lcur[t] = 0;
  __syncthreads();
  for (int i = t; i < cnt; i += 1024)
    atomicAdd(&lcur[(int)((edr[i] >> 16) & (BROWS - 1))], 1);
  __syncthreads();
  if (t < 64) {
    const int v = lcur[t];
    int sc = v;
    #pragma unroll
    for (int d = 1; d < 64; d <<= 1) {
      const int u2 = __shfl_up(sc, d);
      if (t >= d) sc += u2;
    }
    lh[t] = sc - v;
    lcur[t] = sc - v;
    if (t == 63) lh[64] = sc;
  }
  __syncthreads();
  for (int i = t; i < cnt; i += 1024) {
    const u64 p = edr[i];
    const int rl = (int)((p >> 16) & (BROWS - 1));
    const int pos = atomicAdd(&lcur[rl], 1);
    ed[pos] = p;
  }
  __syncthreads();

  const int row = t >> 4;          // 0..63
  const int u = t & 15;
  const int s = u >> 3;            // slot 0/1
  const int l = u & 7;             // 8 lanes split D=64 as 8x8
  float a[8] = {0.f, 0.f, 0.f, 0.f, 0.f, 0.f, 0.f, 0.f};

  int j = lh[row] + s;
  const int je = lh[row + 1];
  uint4 q0 = {0, 0, 0, 0}, q1 = {0, 0, 0, 0};
  float w0 = 0.f, w1 = 0.f;
  if (j < je) {
    const u64 p = ed[j];
    w0 = __uint_as_float((u32)(p >> 32));
    q0 = reinterpret_cast<const uint4*>(he + ((size_t)(p & 0xffffu) << 6))[l];
  }
  if (j + 2 < je) {
    const u64 p = ed[j + 2];
    w1 = __uint_as_float((u32)(p >> 32));
    q1 = reinterpret_cast<const uint4*>(he + ((size_t)(p & 0xffffu) << 6))[l];
  }
  while (j < je) {
    const uint4 qc = q0;
    const float wc = w0;
    q0 = q1; w0 = w1;
    const int jn2 = j + 4;
    if (jn2 < je) {
      const u64 p = ed[jn2];
      w1 = __uint_as_float((u32)(p >> 32));
      q1 = reinterpret_cast<const uint4*>(he + ((size_t)(p & 0xffffu) << 6))[l];
    }
    a[0] = fmaf(wc, __uint_as_float(qc.x << 16), a[0]);
    a[1] = fmaf(wc, __uint_as_float(qc.x & 0xffff0000u), a[1]);
    a[2] = fmaf(wc, __uint_as_float(qc.y << 16), a[2]);
    a[3] = fmaf(wc, __uint_as_float(qc.y & 0xffff0000u), a[3]);
    a[4] = fmaf(wc, __uint_as_float(qc.z << 16), a[4]);
    a[5] = fmaf(wc, __uint_as_float(qc.z & 0xffff0000u), a[5]);
    a[6] = fmaf(wc, __uint_as_float(qc.w << 16), a[6]);
    a[7] = fmaf(wc, __uint_as_float(qc.w & 0xffff0000u), a[7]);
    j += 2;
  }

  // spill-scan: normally nspill == 0 -> one scalar load + skip. Slot 0 only.
  const int ns = nspill[0];
  for (int sidx = 0; sidx < ns; ++sidx) {
    const u64 p = spill[sidx];
    const int grow = (int)((p >> 16) & 0xffffu);
    if ((grow >> BSH) != b) continue;
    if ((grow & (BROWS - 1)) != row || s != 0) continue;
    const float ww = __uint_as_float((u32)(p >> 32));
    const uint4 qq = reinterpret_cast<const uint4*>(he + ((size_t)(p & 0xffffu) << 6))[l];
    a[0] = fmaf(ww, __uint_as_float(qq.x << 16), a[0]);
    a[1] = fmaf(ww, __uint_as_float(qq.x & 0xffff0000u), a[1]);
    a[2] = fmaf(ww, __uint_as_float(qq.y << 16), a[2]);
    a[3] = fmaf(ww, __uint_as_float(qq.y & 0xffff0000u), a[3]);
    a[4] = fmaf(ww, __uint_as_float(qq.z << 16), a[4]);
    a[5] = fmaf(ww, __uint_as_float(qq.z & 0xffff0000u), a[5]);
    a[6] = fmaf(ww, __uint_as_float(qq.w << 16), a[6]);
    a[7] = fmaf(ww, __uint_as_float(qq.w & 0xffff0000u), a[7]);
  }

  // merge the two slots (lanes u and u^8 hold the partials)
  #pragma unroll
  for (int k = 0; k < 8; ++k) a[k] += __shfl_xor(a[k], 8);

  // epilogue: out = proj(expmap0(relu(acc)))  (8-lane reduce for the norm)
  float ss = 0.f;
  #pragma unroll
  for (int k = 0; k < 8; ++k) { a[k] = fmaxf(a[k], 0.f); ss = fmaf(a[k], a[k], ss); }
  ss += __shfl_xor(ss, 1); ss += __shfl_xor(ss, 2); ss += __shfl_xor(ss, 4);
  const float nu = fmaxf(sqrtf(ss), 1e-15f);
  const float th = tanhf(nu);
  const float maxn = 1.0f - 4e-3f;
  const float scale = (th > maxn) ? (maxn / nu) : (th / nu);
  const int grow = (b << BSH) + row;
  if (s == 0 && grow < n) {
    float4* op = reinterpret_cast<float4*>(out + (size_t)grow * DD + (size_t)l * 8);
    op[0] = float4{a[0] * scale, a[1] * scale, a[2] * scale, a[3] * scale};
    op[1] = float4{a[4] * scale, a[5] * scale, a[6] * scale, a[7] * scale};
  }
}

// ---------------------------------------------------------------------------
// Deep fallback (tiny ws): atomic scatter path, fp32.
// ---------------------------------------------------------------------------
__global__ __launch_bounds__(256) void hgcn_linf32(const float* __restrict__ x,
                                                   const float* __restrict__ W,
                                                   float* __restrict__ he, int n) {
  __shared__ float Wl[64][68];
  __shared__ float xs[4][64];
  const int tid = threadIdx.x;
  for (int i = tid; i < 64 * 64; i += 256) Wl[i >> 6][i & 63] = W[i];
  const int wave = tid >> 6, lane = tid & 63;
  const int row = blockIdx.x * 4 + wave;
  float xv = 0.f;
  if (row < n) xv = x[row * DD + lane];
  xs[wave][lane] = xv;
  __syncthreads();
  if (row >= n) return;
  float nx2 = xv * xv;
  #pragma unroll
  for (int m = 1; m < 64; m <<= 1) nx2 += __shfl_xor(nx2, m);
  const float nx = fmaxf(sqrtf(nx2), 1e-15f);
  const float s = atanhf(fminf(nx, 1.f - 1e-7f)) / nx;
  const int j0 = (lane >> 3) & 7;
  float acc = 0.f;
  #pragma unroll
  for (int jj = 0; jj < 16; ++jj) {
    const int k = ((jj + j0) & 15) << 2;
    const float4 xk = *reinterpret_cast<const float4*>(&xs[wave][k]);
    const float4 wk = *reinterpret_cast<const float4*>(&Wl[lane][k]);
    acc = fmaf(xk.x, wk.x, acc); acc = fmaf(xk.y, wk.y, acc);
    acc = fmaf(xk.z, wk.z, acc); acc = fmaf(xk.w, wk.w, acc);
  }
  he[row * DD + lane] = acc * s;
}

__global__ __launch_bounds__(256) void hgcn_zero(float* __restrict__ p, int n4) {
  const int i = blockIdx.x * 256 + threadIdx.x;
  if (i < n4) reinterpret_cast<float4*>(p)[i] = float4{0.f, 0.f, 0.f, 0.f};
}

__global__ __launch_bounds__(256) void hgcn_scatter(const float* __restrict__ he,
                                                    const int* __restrict__ ei,
                                                    const float* __restrict__ ew,
                                                    float* __restrict__ sup, int ne) {
  const int t = blockIdx.x * 256 + threadIdx.x;
  const int e = t >> 4, l = t & 15;
  if (e >= ne) return;
  const int row = ei[e];
  const int col = ei[ne + e];
  const float w = ew[e];
  const float4 v = *reinterpret_cast<const float4*>(he + (size_t)col * DD + l * 4);
  float* dst = sup + (size_t)row * DD + l * 4;
  unsafeAtomicAdd(dst + 0, w * v.x);
  unsafeAtomicAdd(dst + 1, w * v.y);
  unsafeAtomicAdd(dst + 2, w * v.z);
  unsafeAtomicAdd(dst + 3, w * v.w);
}

__global__ __launch_bounds__(256) void hgcn_final(const float* __restrict__ sup,
                                                  float* __restrict__ out, int n) {
  const int t = blockIdx.x * 256 + threadIdx.x;
  const int r = t >> 4, l = t & 15;
  if (r >= n) return;
  float4 v = *reinterpret_cast<const float4*>(sup + (size_t)r * DD + l * 4);
  v.x = fmaxf(v.x, 0.f); v.y = fmaxf(v.y, 0.f);
  v.z = fmaxf(v.z, 0.f); v.w = fmaxf(v.w, 0.f);
  float p = v.x*v.x + v.y*v.y + v.z*v.z + v.w*v.w;
  p += __shfl_xor(p, 1); p += __shfl_xor(p, 2);
  p += __shfl_xor(p, 4); p += __shfl_xor(p, 8);
  const float nu = fmaxf(sqrtf(p), 1e-15f);
  const float th = tanhf(nu);
  float scale = th / nu;
  const float maxn = 1.0f - 4e-3f;
  if (th > maxn) scale = maxn / nu;
  float4 o = {v.x*scale, v.y*scale, v.z*scale, v.w*scale};
  *reinterpret_cast<float4*>(out + (size_t)r * DD + l * 4) = o;
}

extern "C" void kernel_launch(void* const* d_in, const int* in_sizes, int n_in,
                              void* d_out, int out_size, void* d_ws, size_t ws_size,
                              hipStream_t stream) {
  const float* x  = (const float*)d_in[0];
  const float* W  = (const float*)d_in[1];
  const float* ew = (const float*)d_in[2];
  const int*   ei = (const int*)d_in[3];
  const int n  = in_sizes[0] / DD;          // 50000
  const int ne = in_sizes[2];               // 800000
  const int nb = (n + BROWS - 1) / BROWS;   // buckets (782)

  // ws layout (16B-aligned blocks)
  size_t off_he    = 0;
  size_t off_stage = off_he + (((size_t)n * DD * 2 + 15) / 16) * 16;
  size_t off_spill = off_stage + (size_t)MAXB * CAPB * 8;
  size_t off_bcur  = off_spill + (size_t)ne * 8;
  size_t off_nsp   = off_bcur + MAXB * 4;
  size_t need      = off_nsp + 64;

  // performance guard only (overflow is correctness-safe via spill):
  const size_t mean = (size_t)ne / (size_t)nb;
  size_t sig = 1;
  while (sig * sig < mean) ++sig;           // ceil(sqrt(mean))
  const bool capOK = mean + 8 * sig <= CAPB;

  if (ws_size >= need && n <= 65535 && nb <= MAXB && capOK) {
    __hip_bfloat16* he = (__hip_bfloat16*)((char*)d_ws + off_he);
    u64* stage  = (u64*)((char*)d_ws + off_stage);
    u64* spill  = (u64*)((char*)d_ws + off_spill);
    int* bcur   = (int*)((char*)d_ws + off_bcur);
    int* nspill = (int*)((char*)d_ws + off_nsp);
    float* out  = (float*)d_out;

    const int nbin = (ne + BINC - 1) / BINC;        // 261
    const int nlin = (n + LROWS - 1) / LROWS;       // 391

    hipLaunchKernelGGL(hgcn_zero0,  dim3(1),           dim3(1024), 0, stream, bcur, nspill);
    hipLaunchKernelGGL(hgcn_linbin, dim3(nbin + nlin), dim3(512),  0, stream,
                       x, W, he, ei, ew, bcur, stage, spill, nspill, n, ne, nbin);
    hipLaunchKernelGGL(hgcn_bagg,   dim3(nb),          dim3(1024), 0, stream,
                       (const u16*)he, stage, bcur, spill, nspill, out, n);
  } else {
    float* he  = (float*)d_out;
    float* sup = (float*)d_ws;
    float* out = (float*)d_out;
    const int n4 = n * DD / 4;
    hipLaunchKernelGGL(hgcn_zero,    dim3((n4 + 255) / 256),       dim3(256), 0, stream, sup, n4);
    hipLaunchKernelGGL(hgcn_linf32,  dim3((n + 3) / 4),            dim3(256), 0, stream, x, W, he, n);
    hipLaunchKernelGGL(hgcn_scatter, dim3((ne * 16 + 255) / 256),  dim3(256), 0, stream, he, ei, ew, sup, ne);
    hipLaunchKernelGGL(hgcn_final,   dim3((n * 16 + 255) / 256),   dim3(256), 0, stream, sup, out, n);
  }
}

// Round 14
// 60.699 us; speedup vs baseline: 3.2909x; 1.0024x over previous
//
#include <hip/hip_runtime.h>
#include <hip/hip_bf16.h>
#include <math.h>

#define DD 64
#define BROWS 64            // rows per bucket
#define BSH 6               // log2(BROWS)
#define MAXB 1024           // max buckets supported
#define CAPB 1536           // fixed bucket capacity (mean + >8 sigma headroom)
#define BINB 512            // bin block threads
#define BINC 3072           // edges per bin block (6 per thread)
#define LROWS 128           // rows per linear block (8 waves x 16)
typedef unsigned long long u64;
typedef unsigned int u32;
typedef unsigned short u16;
typedef __fp16 f16x2 __attribute__((ext_vector_type(2)));

// ---------------------------------------------------------------------------
// K0: zero bucket cursors + spill counter (1 block; precedes linbin in-stream).
// ---------------------------------------------------------------------------
__global__ __launch_bounds__(1024) void hgcn_zero0(int* __restrict__ bcur,
                                                   int* __restrict__ nspill) {
  const int i = threadIdx.x;
  if (i < MAXB) bcur[i] = 0;
  if (i == 0) nspill[0] = 0;
}

// ---------------------------------------------------------------------------
// Fused linear+bin (disjoint inputs -> blocks co-schedule). R13 structure.
// ---------------------------------------------------------------------------
__global__ __launch_bounds__(512) void hgcn_linbin(const float* __restrict__ x,
                                                   const float* __restrict__ W,
                                                   __hip_bfloat16* __restrict__ he,
                                                   const int* __restrict__ ei,
                                                   const float* __restrict__ ew,
                                                   int* __restrict__ bcur,
                                                   u64* __restrict__ stage,
                                                   u64* __restrict__ spill,
                                                   int* __restrict__ nspill,
                                                   int n, int ne, int nbin) {
  const int tid = threadIdx.x;
  if ((int)blockIdx.x < nbin) {
    // ------------------------------ bin ------------------------------------
    __shared__ int h[MAXB], gp[MAXB];
    h[tid] = 0; h[tid + 512] = 0;
    __syncthreads();
    const int eb = blockIdx.x * BINC;
    const int m = min(BINC, ne - eb);
    int r[6], c[6], rk[6];
    float w[6];
    int cnt = 0;
    #pragma unroll
    for (int k = 0; k < 6; ++k) {
      const int i = tid + k * BINB;
      if (i < m) {
        r[k] = ei[eb + i];
        c[k] = ei[ne + eb + i];
        w[k] = ew[eb + i];
        rk[k] = atomicAdd(&h[r[k] >> BSH], 1);   // rank within block
        cnt = k + 1;
      }
    }
    __syncthreads();
    {
      const int v0 = h[tid];
      gp[tid] = v0 ? atomicAdd(&bcur[tid], v0) : 0;
      const int v1 = h[tid + 512];
      gp[tid + 512] = v1 ? atomicAdd(&bcur[tid + 512], v1) : 0;
    }
    __syncthreads();
    for (int k = 0; k < cnt; ++k) {
      const int b = r[k] >> BSH;
      const int pos = gp[b] + rk[k];
      if (pos < CAPB) {
        stage[(size_t)b * CAPB + pos] =
            ((u64)__float_as_uint(w[k]) << 32) | ((u32)(r[k] & (BROWS - 1)) << 16) | (u32)c[k];
      } else {
        const int sp = atomicAdd(nspill, 1);
        spill[sp] = ((u64)__float_as_uint(w[k]) << 32) | ((u32)(r[k] & 0xffff) << 16) | (u32)c[k];
      }
    }
  } else {
    // ----------------------------- linear ----------------------------------
    __shared__ f16x2 xsh[8][32];
    const int lb = (int)blockIdx.x - nbin;
    const int wave = tid >> 6, lane = tid & 63;
    f16x2 Wh[32];                       // W column `lane` as packed f16 pairs
    #pragma unroll
    for (int m4 = 0; m4 < 16; ++m4) {
      const float4 wv = *reinterpret_cast<const float4*>(W + lane * 64 + m4 * 4);
      Wh[2 * m4]     = __builtin_amdgcn_cvt_pkrtz(wv.x, wv.y);
      Wh[2 * m4 + 1] = __builtin_amdgcn_cvt_pkrtz(wv.z, wv.w);
    }
    const int rbase = lb * LROWS + wave * 16;
    for (int q = 0; q < 16; ++q) {
      const int row = rbase + q;
      const bool ok = row < n;
      const float xv = ok ? x[(size_t)row * DD + lane] : 0.f;
      float nx2 = xv * xv;
      #pragma unroll
      for (int mm = 1; mm < 64; mm <<= 1) nx2 += __shfl_xor(nx2, mm);
      const float nx = fmaxf(sqrtf(nx2), 1e-15f);
      const float z  = fminf(nx, 1.f - 1e-7f);
      const float s  = 0.5f * __logf((1.f + z) / (1.f - z)) / nx;
      const float xo = __shfl_xor(xv, 1);
      if (!(lane & 1)) xsh[wave][lane >> 1] = __builtin_amdgcn_cvt_pkrtz(xv, xo);
      float acc = 0.f;
      #pragma unroll
      for (int m2 = 0; m2 < 32; ++m2)
        acc = __builtin_amdgcn_fdot2(xsh[wave][m2], Wh[m2], acc, false);
      if (ok) he[(size_t)row * DD + lane] = __float2bfloat16(acc * s);
    }
  }
}

// ---------------------------------------------------------------------------
// Bucket aggregate + fused epilogue (NO fp atomics).
// ONE-PASS sort: each thread holds its <=2 edges in registers; the hist
// atomicAdd returns the within-row rank (same trick as bin); after the scan,
// place directly at lh[row]+rank. Deletes the edr array, one LDS round-trip,
// and the cursor-atomic pass. Gather: 2 slots x depth-2 prefetch per row.
// ---------------------------------------------------------------------------
__global__ __launch_bounds__(1024) void hgcn_bagg(const u16* __restrict__ he,
                                                  const u64* __restrict__ stage,
                                                  const int* __restrict__ bcur,
                                                  const u64* __restrict__ spill,
                                                  const int* __restrict__ nspill,
                                                  float* __restrict__ out, int n) {
  __shared__ u64 ed[CAPB];
  __shared__ int lh[BROWS + 1];
  __shared__ int lcnt[BROWS];
  const int t = threadIdx.x;
  const int b = blockIdx.x;
  const u64* sb = stage + (size_t)b * CAPB;
  const int cnt = min(bcur[b], CAPB);

  if (t < BROWS) lcnt[t] = 0;
  __syncthreads();
  u64 p0 = 0, p1 = 0;
  int rk0 = -1, rk1 = -1;
  if (t < cnt) {
    p0 = sb[t];
    rk0 = atomicAdd(&lcnt[(int)((p0 >> 16) & (BROWS - 1))], 1);
  }
  if (t + 1024 < cnt) {
    p1 = sb[t + 1024];
    rk1 = atomicAdd(&lcnt[(int)((p1 >> 16) & (BROWS - 1))], 1);
  }
  __syncthreads();
  if (t < 64) {                        // wave-scan 64 row counts -> exclusive
    const int v = lcnt[t];
    int sc = v;
    #pragma unroll
    for (int d = 1; d < 64; d <<= 1) {
      const int u2 = __shfl_up(sc, d);
      if (t >= d) sc += u2;
    }
    lh[t] = sc - v;
    if (t == 63) lh[64] = sc;
  }
  __syncthreads();
  if (rk0 >= 0) ed[lh[(int)((p0 >> 16) & (BROWS - 1))] + rk0] = p0;
  if (rk1 >= 0) ed[lh[(int)((p1 >> 16) & (BROWS - 1))] + rk1] = p1;
  __syncthreads();

  const int row = t >> 4;          // 0..63
  const int u = t & 15;
  const int s = u >> 3;            // slot 0/1
  const int l = u & 7;             // 8 lanes split D=64 as 8x8
  float a[8] = {0.f, 0.f, 0.f, 0.f, 0.f, 0.f, 0.f, 0.f};

  int j = lh[row] + s;
  const int je = lh[row + 1];
  uint4 q0 = {0, 0, 0, 0}, q1 = {0, 0, 0, 0};
  float w0 = 0.f, w1 = 0.f;
  if (j < je) {
    const u64 p = ed[j];
    w0 = __uint_as_float((u32)(p >> 32));
    q0 = reinterpret_cast<const uint4*>(he + ((size_t)(p & 0xffffu) << 6))[l];
  }
  if (j + 2 < je) {
    const u64 p = ed[j + 2];
    w1 = __uint_as_float((u32)(p >> 32));
    q1 = reinterpret_cast<const uint4*>(he + ((size_t)(p & 0xffffu) << 6))[l];
  }
  while (j < je) {
    const uint4 qc = q0;
    const float wc = w0;
    q0 = q1; w0 = w1;
    const int jn2 = j + 4;
    if (jn2 < je) {
      const u64 p = ed[jn2];
      w1 = __uint_as_float((u32)(p >> 32));
      q1 = reinterpret_cast<const uint4*>(he + ((size_t)(p & 0xffffu) << 6))[l];
    }
    a[0] = fmaf(wc, __uint_as_float(qc.x << 16), a[0]);
    a[1] = fmaf(wc, __uint_as_float(qc.x & 0xffff0000u), a[1]);
    a[2] = fmaf(wc, __uint_as_float(qc.y << 16), a[2]);
    a[3] = fmaf(wc, __uint_as_float(qc.y & 0xffff0000u), a[3]);
    a[4] = fmaf(wc, __uint_as_float(qc.z << 16), a[4]);
    a[5] = fmaf(wc, __uint_as_float(qc.z & 0xffff0000u), a[5]);
    a[6] = fmaf(wc, __uint_as_float(qc.w << 16), a[6]);
    a[7] = fmaf(wc, __uint_as_float(qc.w & 0xffff0000u), a[7]);
    j += 2;
  }

  // spill-scan: normally nspill == 0 -> one scalar load + skip. Slot 0 only.
  const int ns = nspill[0];
  for (int sidx = 0; sidx < ns; ++sidx) {
    const u64 p = spill[sidx];
    const int grow = (int)((p >> 16) & 0xffffu);
    if ((grow >> BSH) != b) continue;
    if ((grow & (BROWS - 1)) != row || s != 0) continue;
    const float ww = __uint_as_float((u32)(p >> 32));
    const uint4 qq = reinterpret_cast<const uint4*>(he + ((size_t)(p & 0xffffu) << 6))[l];
    a[0] = fmaf(ww, __uint_as_float(qq.x << 16), a[0]);
    a[1] = fmaf(ww, __uint_as_float(qq.x & 0xffff0000u), a[1]);
    a[2] = fmaf(ww, __uint_as_float(qq.y << 16), a[2]);
    a[3] = fmaf(ww, __uint_as_float(qq.y & 0xffff0000u), a[3]);
    a[4] = fmaf(ww, __uint_as_float(qq.z << 16), a[4]);
    a[5] = fmaf(ww, __uint_as_float(qq.z & 0xffff0000u), a[5]);
    a[6] = fmaf(ww, __uint_as_float(qq.w << 16), a[6]);
    a[7] = fmaf(ww, __uint_as_float(qq.w & 0xffff0000u), a[7]);
  }

  // merge the two slots (lanes u and u^8 hold the partials)
  #pragma unroll
  for (int k = 0; k < 8; ++k) a[k] += __shfl_xor(a[k], 8);

  // epilogue: out = proj(expmap0(relu(acc)))  (8-lane reduce for the norm)
  float ss = 0.f;
  #pragma unroll
  for (int k = 0; k < 8; ++k) { a[k] = fmaxf(a[k], 0.f); ss = fmaf(a[k], a[k], ss); }
  ss += __shfl_xor(ss, 1); ss += __shfl_xor(ss, 2); ss += __shfl_xor(ss, 4);
  const float nu = fmaxf(sqrtf(ss), 1e-15f);
  const float th = tanhf(nu);
  const float maxn = 1.0f - 4e-3f;
  const float scale = (th > maxn) ? (maxn / nu) : (th / nu);
  const int grow = (b << BSH) + row;
  if (s == 0 && grow < n) {
    float4* op = reinterpret_cast<float4*>(out + (size_t)grow * DD + (size_t)l * 8);
    op[0] = float4{a[0] * scale, a[1] * scale, a[2] * scale, a[3] * scale};
    op[1] = float4{a[4] * scale, a[5] * scale, a[6] * scale, a[7] * scale};
  }
}

// ---------------------------------------------------------------------------
// Deep fallback (tiny ws): atomic scatter path, fp32.
// ---------------------------------------------------------------------------
__global__ __launch_bounds__(256) void hgcn_linf32(const float* __restrict__ x,
                                                   const float* __restrict__ W,
                                                   float* __restrict__ he, int n) {
  __shared__ float Wl[64][68];
  __shared__ float xs[4][64];
  const int tid = threadIdx.x;
  for (int i = tid; i < 64 * 64; i += 256) Wl[i >> 6][i & 63] = W[i];
  const int wave = tid >> 6, lane = tid & 63;
  const int row = blockIdx.x * 4 + wave;
  float xv = 0.f;
  if (row < n) xv = x[row * DD + lane];
  xs[wave][lane] = xv;
  __syncthreads();
  if (row >= n) return;
  float nx2 = xv * xv;
  #pragma unroll
  for (int m = 1; m < 64; m <<= 1) nx2 += __shfl_xor(nx2, m);
  const float nx = fmaxf(sqrtf(nx2), 1e-15f);
  const float s = atanhf(fminf(nx, 1.f - 1e-7f)) / nx;
  const int j0 = (lane >> 3) & 7;
  float acc = 0.f;
  #pragma unroll
  for (int jj = 0; jj < 16; ++jj) {
    const int k = ((jj + j0) & 15) << 2;
    const float4 xk = *reinterpret_cast<const float4*>(&xs[wave][k]);
    const float4 wk = *reinterpret_cast<const float4*>(&Wl[lane][k]);
    acc = fmaf(xk.x, wk.x, acc); acc = fmaf(xk.y, wk.y, acc);
    acc = fmaf(xk.z, wk.z, acc); acc = fmaf(xk.w, wk.w, acc);
  }
  he[row * DD + lane] = acc * s;
}

__global__ __launch_bounds__(256) void hgcn_zero(float* __restrict__ p, int n4) {
  const int i = blockIdx.x * 256 + threadIdx.x;
  if (i < n4) reinterpret_cast<float4*>(p)[i] = float4{0.f, 0.f, 0.f, 0.f};
}

__global__ __launch_bounds__(256) void hgcn_scatter(const float* __restrict__ he,
                                                    const int* __restrict__ ei,
                                                    const float* __restrict__ ew,
                                                    float* __restrict__ sup, int ne) {
  const int t = blockIdx.x * 256 + threadIdx.x;
  const int e = t >> 4, l = t & 15;
  if (e >= ne) return;
  const int row = ei[e];
  const int col = ei[ne + e];
  const float w = ew[e];
  const float4 v = *reinterpret_cast<const float4*>(he + (size_t)col * DD + l * 4);
  float* dst = sup + (size_t)row * DD + l * 4;
  unsafeAtomicAdd(dst + 0, w * v.x);
  unsafeAtomicAdd(dst + 1, w * v.y);
  unsafeAtomicAdd(dst + 2, w * v.z);
  unsafeAtomicAdd(dst + 3, w * v.w);
}

__global__ __launch_bounds__(256) void hgcn_final(const float* __restrict__ sup,
                                                  float* __restrict__ out, int n) {
  const int t = blockIdx.x * 256 + threadIdx.x;
  const int r = t >> 4, l = t & 15;
  if (r >= n) return;
  float4 v = *reinterpret_cast<const float4*>(sup + (size_t)r * DD + l * 4);
  v.x = fmaxf(v.x, 0.f); v.y = fmaxf(v.y, 0.f);
  v.z = fmaxf(v.z, 0.f); v.w = fmaxf(v.w, 0.f);
  float p = v.x*v.x + v.y*v.y + v.z*v.z + v.w*v.w;
  p += __shfl_xor(p, 1); p += __shfl_xor(p, 2);
  p += __shfl_xor(p, 4); p += __shfl_xor(p, 8);
  const float nu = fmaxf(sqrtf(p), 1e-15f);
  const float th = tanhf(nu);
  float scale = th / nu;
  const float maxn = 1.0f - 4e-3f;
  if (th > maxn) scale = maxn / nu;
  float4 o = {v.x*scale, v.y*scale, v.z*scale, v.w*scale};
  *reinterpret_cast<float4*>(out + (size_t)r * DD + l * 4) = o;
}

extern "C" void kernel_launch(void* const* d_in, const int* in_sizes, int n_in,
                              void* d_out, int out_size, void* d_ws, size_t ws_size,
                              hipStream_t stream) {
  const float* x  = (const float*)d_in[0];
  const float* W  = (const float*)d_in[1];
  const float* ew = (const float*)d_in[2];
  const int*   ei = (const int*)d_in[3];
  const int n  = in_sizes[0] / DD;          // 50000
  const int ne = in_sizes[2];               // 800000
  const int nb = (n + BROWS - 1) / BROWS;   // buckets (782)

  // ws layout (16B-aligned blocks)
  size_t off_he    = 0;
  size_t off_stage = off_he + (((size_t)n * DD * 2 + 15) / 16) * 16;
  size_t off_spill = off_stage + (size_t)MAXB * CAPB * 8;
  size_t off_bcur  = off_spill + (size_t)ne * 8;
  size_t off_nsp   = off_bcur + MAXB * 4;
  size_t need      = off_nsp + 64;

  // performance guard only (overflow is correctness-safe via spill):
  const size_t mean = (size_t)ne / (size_t)nb;
  size_t sig = 1;
  while (sig * sig < mean) ++sig;           // ceil(sqrt(mean))
  const bool capOK = mean + 8 * sig <= CAPB;

  if (ws_size >= need && n <= 65535 && nb <= MAXB && capOK) {
    __hip_bfloat16* he = (__hip_bfloat16*)((char*)d_ws + off_he);
    u64* stage  = (u64*)((char*)d_ws + off_stage);
    u64* spill  = (u64*)((char*)d_ws + off_spill);
    int* bcur   = (int*)((char*)d_ws + off_bcur);
    int* nspill = (int*)((char*)d_ws + off_nsp);
    float* out  = (float*)d_out;

    const int nbin = (ne + BINC - 1) / BINC;        // 261
    const int nlin = (n + LROWS - 1) / LROWS;       // 391

    hipLaunchKernelGGL(hgcn_zero0,  dim3(1),           dim3(1024), 0, stream, bcur, nspill);
    hipLaunchKernelGGL(hgcn_linbin, dim3(nbin + nlin), dim3(512),  0, stream,
                       x, W, he, ei, ew, bcur, stage, spill, nspill, n, ne, nbin);
    hipLaunchKernelGGL(hgcn_bagg,   dim3(nb),          dim3(1024), 0, stream,
                       (const u16*)he, stage, bcur, spill, nspill, out, n);
  } else {
    float* he  = (float*)d_out;
    float* sup = (float*)d_ws;
    float* out = (float*)d_out;
    const int n4 = n * DD / 4;
    hipLaunchKernelGGL(hgcn_zero,    dim3((n4 + 255) / 256),       dim3(256), 0, stream, sup, n4);
    hipLaunchKernelGGL(hgcn_linf32,  dim3((n + 3) / 4),            dim3(256), 0, stream, x, W, he, n);
    hipLaunchKernelGGL(hgcn_scatter, dim3((ne * 16 + 255) / 256),  dim3(256), 0, stream, he, ei, ew, sup, ne);
    hipLaunchKernelGGL(hgcn_final,   dim3((n * 16 + 255) / 256),   dim3(256), 0, stream, sup, out, n);
  }
}